// Round 5
// baseline (343.824 us; speedup 1.0000x reference)
//
#include <hip/hip_runtime.h>

// CostTokenizer R5: R4's 2-px vertical blocking with the spill fixed.
//  - VGPR budget is quantized 64/128/256: launch_bounds(256,2) -> 256 budget.
//    (R2's (256,4) and R4's (256,3) both spilled acc arrays -> 600-990 MB HBM.)
//  - rolling-window halo reads: only 2 float4 live in the (a,b) loop
//    (R4 buffered 8 -> +32 regs over the 128 budget).
//  - halo row stride 26 float4 (104 floats = 8 mod 32): the 4 ty-groups of a
//    wave b128 phase start at banks 0/8/16/24 -> 2-way = free
//    (stride 23 gave ~4-way overlap, 5.6M conflict cycles in R3).
//  - LDS union (reduction aliases dead halos, 50.2 KB) + XCD column swizzle.
//
//  corr[k] = sum_c f1[c,h,w] * f2[c, (h-dy)%H, (w-dx)%W], k = (dy+3)*7 + (dx+3)
//  tok[t,b,d,h,w] = b[d] + (1/sqrt(C)) * sum_k corr[k] * w[k,d]

#define TD 192
#define HSTRIDE 26   // halo row stride in float4

template<int C, int H, int W, int TX, int TY>
__device__ __forceinline__ void level_tile(
    const float* __restrict__ lvl, const float* __restrict__ wm,
    const float* __restrict__ bias, float* __restrict__ out,
    int r, float scale, float* __restrict__ smem)
{
    const int HW = H * W;
    // XCD column-affinity: tiles of one column (pair,tX) are == mod 8 in bid
    const int xcd = r & 7, q = r >> 3;
    const int tY  = q % TY;
    const int col = (q / TY) * 8 + xcd;      // [0, 4*TX)
    const int pair = col / TX, tX = col % TX;

    const int t  = pair >> 1, bb = pair & 1;
    const float* f1 = lvl + (t * 2 + bb) * C * HW;
    const float* f2 = lvl + ((t + 1) * 2 + bb) * C * HW;

    const int tid  = threadIdx.x;
    const int lane = tid & 63;
    const int g    = tid >> 6;               // wave: channel group / d group
    const int tx   = lane & 15, tyy = lane >> 4;  // lane owns rows 2tyy, 2tyy+1
    const int x0   = tX * 16, y0 = tY * 8;
    const int x    = x0 + tx;
    const int y    = y0 + 2 * tyy;

    float4* h = (float4*)smem + g * (14 * HSTRIDE);  // wave halo: 14 rows

    // staging offsets for halo cells p in [0,308): row=p/22, col=p%22
    int goff[5], loff[5];
#pragma unroll
    for (int i = 0; i < 5; ++i) {
        int p = lane + i * 64;
        int rr = p / 22, cc = p - rr * 22;
        int gy = y0 - 3 + rr; if (gy < 0) gy += H; if (gy >= H) gy -= H;
        int gx = x0 - 3 + cc; if (gx < 0) gx += W; if (gx >= W) gx -= W;
        goff[i] = gy * W + gx;
        loff[i] = rr * HSTRIDE + cc;
    }

    float acc0[49], acc1[49];
#pragma unroll
    for (int k = 0; k < 49; ++k) { acc0[k] = 0.f; acc1[k] = 0.f; }

    // ---- phase 1: correlation, wave-synchronous (wave-private halo) ----
    const int NCH = C / 16;                  // 4-channel chunks per wave
    const float* f2c = f2 + g * (C / 4) * HW;
    const float* f1c = f1 + g * (C / 4) * HW + y * W + x;
#pragma unroll 1
    for (int cg = 0; cg < NCH; ++cg) {
#pragma unroll
        for (int i = 0; i < 5; ++i) {
            if (i < 4 || lane < 52) {
                const float* s = f2c + goff[i];
                float4 v; v.x = s[0]; v.y = s[HW]; v.z = s[2 * HW]; v.w = s[3 * HW];
                h[loff[i]] = v;
            }
        }
        float a00 = f1c[0], a01 = f1c[HW], a02 = f1c[2 * HW], a03 = f1c[3 * HW];
        float a10 = f1c[W], a11 = f1c[HW + W], a12 = f1c[2 * HW + W], a13 = f1c[3 * HW + W];
        f2c += 4 * HW; f1c += 4 * HW;
        // same-wave LDS RAW: compiler lgkmcnt waits cover it
#pragma unroll 1
        for (int b = 0; b < 7; ++b) {
            const float4* hp = h + (2 * tyy) * HSTRIDE + (tx + 6 - b);
            // rolling window down the 8 rows: only 2 float4 live
            float4 hi = hp[7 * HSTRIDE];
#pragma unroll
            for (int a = 0; a < 7; ++a) {
                float4 lo = hp[(6 - a) * HSTRIDE];
                float s0 = acc0[a * 7 + b], s1 = acc1[a * 7 + b];
                s0 = fmaf(a00, lo.x, s0); s0 = fmaf(a01, lo.y, s0);
                s0 = fmaf(a02, lo.z, s0); s0 = fmaf(a03, lo.w, s0);
                s1 = fmaf(a10, hi.x, s1); s1 = fmaf(a11, hi.y, s1);
                s1 = fmaf(a12, hi.z, s1); s1 = fmaf(a13, hi.w, s1);
                acc0[a * 7 + b] = s0; acc1[a * 7 + b] = s1;
                hi = lo;
            }
        }
    }

    // ---- phase 2: cross-wave reduce; slices alias dead halo space ----
    __syncthreads();                         // all waves done with halos
    float* s0p = smem;                       // [49][128]
    float* s1p = smem + 49 * 128;
    if (g >= 2) {
        float* dst = (g == 2) ? s0p : s1p;
#pragma unroll 1
        for (int k = 0; k < 49; ++k) {
            dst[k * 128 + lane]      = acc0[k];
            dst[k * 128 + 64 + lane] = acc1[k];
        }
    }
    __syncthreads();
    if (g < 2) {
        float* dst = (g == 0) ? s0p : s1p;
#pragma unroll 1
        for (int k = 0; k < 49; ++k) {
            dst[k * 128 + lane]      += acc0[k];
            dst[k * 128 + 64 + lane] += acc1[k];
        }
    }
    __syncthreads();

    // ---- phase 3: 49 -> 192, wave g owns d in [48g, 48g+48), 2 px/lane ----
    const int dbase = __builtin_amdgcn_readfirstlane(g * 48);
    float sA[48], sB[48];
#pragma unroll
    for (int j = 0; j < 48; ++j) { float bv = bias[dbase + j]; sA[j] = bv; sB[j] = bv; }
#pragma unroll 1
    for (int k = 0; k < 49; ++k) {
        float c0 = (s0p[k * 128 + lane]      + s1p[k * 128 + lane])      * scale;
        float c1 = (s0p[k * 128 + 64 + lane] + s1p[k * 128 + 64 + lane]) * scale;
        const float* wr = wm + k * TD + dbase;   // wave-uniform -> s_load
#pragma unroll
        for (int j = 0; j < 48; ++j) {
            float wv = wr[j];
            sA[j] = fmaf(wv, c0, sA[j]);
            sB[j] = fmaf(wv, c1, sB[j]);
        }
    }
    float* op = out + (pair * TD + dbase) * HW + y * W + x;
#pragma unroll 1
    for (int j = 0; j < 48; ++j) { op[j * HW] = sA[j]; op[j * HW + W] = sB[j]; }
}

__global__ __launch_bounds__(256, 2)
void cost_tokenizer(const float* __restrict__ l1, const float* __restrict__ l2,
                    const float* __restrict__ l3,
                    const float* __restrict__ w1, const float* __restrict__ b1,
                    const float* __restrict__ w2, const float* __restrict__ b2,
                    const float* __restrict__ w3, const float* __restrict__ b3,
                    float* __restrict__ out)
{
    __shared__ __align__(16) float smem[12544];  // max(2*49*128, 4*14*26*4) f = 50.2 KB
    int bid = blockIdx.x;
    // heavy levels first: L3 (12 chunks/wave), L2 (8), L1 (4)
    if (bid < 32) {
        level_tile<192, 32, 32, 2, 4>(l3, w3, b3, out + 15728640,
                                      bid, 0.072168783648703216f, smem);
    } else if (bid < 160) {
        level_tile<128, 64, 64, 4, 8>(l2, w2, b2, out + 12582912,
                                      bid - 32, 0.088388347648318447f, smem);
    } else {
        level_tile<64, 128, 128, 8, 16>(l1, w1, b1, out,
                                        bid - 160, 0.125f, smem);
    }
}

extern "C" void kernel_launch(void* const* d_in, const int* in_sizes, int n_in,
                              void* d_out, int out_size, void* d_ws, size_t ws_size,
                              hipStream_t stream)
{
    const float* l1 = (const float*)d_in[0];
    const float* l2 = (const float*)d_in[1];
    const float* l3 = (const float*)d_in[2];
    const float* w1 = (const float*)d_in[3];
    const float* b1 = (const float*)d_in[4];
    const float* w2 = (const float*)d_in[5];
    const float* b2 = (const float*)d_in[6];
    const float* w3 = (const float*)d_in[7];
    const float* b3 = (const float*)d_in[8];
    float* out = (float*)d_out;

    hipLaunchKernelGGL(cost_tokenizer, dim3(672), dim3(256), 0, stream,
                       l1, l2, l3, w1, b1, w2, b2, w3, b3, out);
}

// Round 6
// 160.648 us; speedup vs baseline: 2.1402x; 2.1402x over previous
//
#include <hip/hip_runtime.h>

// CostTokenizer R6: R5 dataflow with the TRUE spill cause fixed.
//   Root cause R4/R5: `#pragma unroll 1` on loops whose bodies index
//   per-thread arrays (acc0[a*7+b], acc0[k], sA[j]) with the loop variable
//   -> dynamic register indexing -> compiler places the array in SCRATCH
//   (WRITE_SIZE 595 MB, VALUBusy 9%). Rule: every loop that indexes a
//   register-resident array MUST be fully unrolled; `unroll 1` is only safe
//   when the body touches LDS/global alone.
//  - 2-px vertical blocking: 56 ds_read_b128 feed 98 accumulators per chunk.
//  - halo row stride 26 float4 (104 floats = 8 mod 32): ty-groups at banks
//    0/8/16/24 -> 2-way bank aliasing = free.
//  - LDS union (reduce slices alias dead halos, 50.2 KB) + XCD column swizzle.
//
//  corr[k] = sum_c f1[c,h,w] * f2[c, (h-dy)%H, (w-dx)%W], k = (dy+3)*7 + (dx+3)
//  tok[t,b,d,h,w] = b[d] + (1/sqrt(C)) * sum_k corr[k] * w[k,d]

#define TD 192
#define HSTRIDE 26   // halo row stride in float4

template<int C, int H, int W, int TX, int TY>
__device__ __forceinline__ void level_tile(
    const float* __restrict__ lvl, const float* __restrict__ wm,
    const float* __restrict__ bias, float* __restrict__ out,
    int r, float scale, float* __restrict__ smem)
{
    const int HW = H * W;
    // XCD column-affinity: tiles of one column (pair,tX) are == mod 8 in bid
    const int xcd = r & 7, q = r >> 3;
    const int tY  = q % TY;
    const int col = (q / TY) * 8 + xcd;      // [0, 4*TX)
    const int pair = col / TX, tX = col % TX;

    const int t  = pair >> 1, bb = pair & 1;
    const float* f1 = lvl + (t * 2 + bb) * C * HW;
    const float* f2 = lvl + ((t + 1) * 2 + bb) * C * HW;

    const int tid  = threadIdx.x;
    const int lane = tid & 63;
    const int g    = tid >> 6;               // wave: channel group / d group
    const int tx   = lane & 15, tyy = lane >> 4;  // lane owns rows 2tyy, 2tyy+1
    const int x0   = tX * 16, y0 = tY * 8;
    const int x    = x0 + tx;
    const int y    = y0 + 2 * tyy;

    float4* h = (float4*)smem + g * (14 * HSTRIDE);  // wave halo: 14 rows

    // staging offsets for halo cells p in [0,308): row=p/22, col=p%22
    int goff[5], loff[5];
#pragma unroll
    for (int i = 0; i < 5; ++i) {
        int p = lane + i * 64;
        int rr = p / 22, cc = p - rr * 22;
        int gy = y0 - 3 + rr; if (gy < 0) gy += H; if (gy >= H) gy -= H;
        int gx = x0 - 3 + cc; if (gx < 0) gx += W; if (gx >= W) gx -= W;
        goff[i] = gy * W + gx;
        loff[i] = rr * HSTRIDE + cc;
    }

    float acc0[49], acc1[49];
#pragma unroll
    for (int k = 0; k < 49; ++k) { acc0[k] = 0.f; acc1[k] = 0.f; }

    // ---- phase 1: correlation, wave-synchronous (wave-private halo) ----
    const int NCH = C / 16;                  // 4-channel chunks per wave
    const float* f2c = f2 + g * (C / 4) * HW;
    const float* f1c = f1 + g * (C / 4) * HW + y * W + x;
#pragma unroll 1
    for (int cg = 0; cg < NCH; ++cg) {       // body touches LDS/global only via
#pragma unroll                               // fully-unrolled inner loops
        for (int i = 0; i < 5; ++i) {
            if (i < 4 || lane < 52) {
                const float* s = f2c + goff[i];
                float4 v; v.x = s[0]; v.y = s[HW]; v.z = s[2 * HW]; v.w = s[3 * HW];
                h[loff[i]] = v;
            }
        }
        float a00 = f1c[0], a01 = f1c[HW], a02 = f1c[2 * HW], a03 = f1c[3 * HW];
        float a10 = f1c[W], a11 = f1c[HW + W], a12 = f1c[2 * HW + W], a13 = f1c[3 * HW + W];
        f2c += 4 * HW; f1c += 4 * HW;
        // same-wave LDS RAW: compiler lgkmcnt waits cover it
#pragma unroll
        for (int b = 0; b < 7; ++b) {        // FULL unroll: indexes acc0/acc1
            const float4* hp = h + (2 * tyy) * HSTRIDE + (tx + 6 - b);
            // rolling window down the 8 rows: 2 float4 live per step
            float4 hi = hp[7 * HSTRIDE];
#pragma unroll
            for (int a = 0; a < 7; ++a) {
                float4 lo = hp[(6 - a) * HSTRIDE];
                float s0 = acc0[a * 7 + b], s1 = acc1[a * 7 + b];
                s0 = fmaf(a00, lo.x, s0); s0 = fmaf(a01, lo.y, s0);
                s0 = fmaf(a02, lo.z, s0); s0 = fmaf(a03, lo.w, s0);
                s1 = fmaf(a10, hi.x, s1); s1 = fmaf(a11, hi.y, s1);
                s1 = fmaf(a12, hi.z, s1); s1 = fmaf(a13, hi.w, s1);
                acc0[a * 7 + b] = s0; acc1[a * 7 + b] = s1;
                hi = lo;
            }
        }
    }

    // ---- phase 2: cross-wave reduce; slices alias dead halo space ----
    __syncthreads();                         // all waves done with halos
    float* s0p = smem;                       // [49][128]
    float* s1p = smem + 49 * 128;
    if (g >= 2) {
        float* dst = (g == 2) ? s0p : s1p;
#pragma unroll
        for (int k = 0; k < 49; ++k) {       // FULL unroll: indexes acc0/acc1
            dst[k * 128 + lane]      = acc0[k];
            dst[k * 128 + 64 + lane] = acc1[k];
        }
    }
    __syncthreads();
    if (g < 2) {
        float* dst = (g == 0) ? s0p : s1p;
#pragma unroll
        for (int k = 0; k < 49; ++k) {       // FULL unroll: indexes acc0/acc1
            dst[k * 128 + lane]      += acc0[k];
            dst[k * 128 + 64 + lane] += acc1[k];
        }
    }
    __syncthreads();

    // ---- phase 3: 49 -> 192, wave g owns d in [48g, 48g+48), 2 px/lane ----
    const int dbase = __builtin_amdgcn_readfirstlane(g * 48);
    float sA[48], sB[48];
#pragma unroll
    for (int j = 0; j < 48; ++j) { float bv = bias[dbase + j]; sA[j] = bv; sB[j] = bv; }
#pragma unroll 1
    for (int k = 0; k < 49; ++k) {           // rolled OK: k only indexes LDS/global
        float c0 = (s0p[k * 128 + lane]      + s1p[k * 128 + lane])      * scale;
        float c1 = (s0p[k * 128 + 64 + lane] + s1p[k * 128 + 64 + lane]) * scale;
        const float* wr = wm + k * TD + dbase;   // wave-uniform -> s_load
#pragma unroll
        for (int j = 0; j < 48; ++j) {       // FULL unroll: indexes sA/sB
            float wv = wr[j];
            sA[j] = fmaf(wv, c0, sA[j]);
            sB[j] = fmaf(wv, c1, sB[j]);
        }
    }
    float* op = out + (pair * TD + dbase) * HW + y * W + x;
#pragma unroll
    for (int j = 0; j < 48; ++j) {           // FULL unroll: indexes sA/sB
        op[j * HW] = sA[j]; op[j * HW + W] = sB[j];
    }
}

__global__ __launch_bounds__(256, 2)
void cost_tokenizer(const float* __restrict__ l1, const float* __restrict__ l2,
                    const float* __restrict__ l3,
                    const float* __restrict__ w1, const float* __restrict__ b1,
                    const float* __restrict__ w2, const float* __restrict__ b2,
                    const float* __restrict__ w3, const float* __restrict__ b3,
                    float* __restrict__ out)
{
    __shared__ __align__(16) float smem[12544];  // max(2*49*128, 4*14*26*4) f = 50.2 KB
    int bid = blockIdx.x;
    // heavy levels first: L3 (12 chunks/wave), L2 (8), L1 (4)
    if (bid < 32) {
        level_tile<192, 32, 32, 2, 4>(l3, w3, b3, out + 15728640,
                                      bid, 0.072168783648703216f, smem);
    } else if (bid < 160) {
        level_tile<128, 64, 64, 4, 8>(l2, w2, b2, out + 12582912,
                                      bid - 32, 0.088388347648318447f, smem);
    } else {
        level_tile<64, 128, 128, 8, 16>(l1, w1, b1, out,
                                        bid - 160, 0.125f, smem);
    }
}

extern "C" void kernel_launch(void* const* d_in, const int* in_sizes, int n_in,
                              void* d_out, int out_size, void* d_ws, size_t ws_size,
                              hipStream_t stream)
{
    const float* l1 = (const float*)d_in[0];
    const float* l2 = (const float*)d_in[1];
    const float* l3 = (const float*)d_in[2];
    const float* w1 = (const float*)d_in[3];
    const float* b1 = (const float*)d_in[4];
    const float* w2 = (const float*)d_in[5];
    const float* b2 = (const float*)d_in[6];
    const float* w3 = (const float*)d_in[7];
    const float* b3 = (const float*)d_in[8];
    float* out = (float*)d_out;

    hipLaunchKernelGGL(cost_tokenizer, dim3(672), dim3(256), 0, stream,
                       l1, l2, l3, w1, b1, w2, b2, w3, b3, out);
}